// Round 6
// baseline (660.153 us; speedup 1.0000x reference)
//
#include <hip/hip_runtime.h>

#define VOCAB 32000
#define EMB 32
#define HID 16
#define SEQ 128
#define BATCH 32
#define NROW (SEQ * BATCH)  // 4096 rows = (t, b) pairs

// ---------------------------------------------------------------------------
// K1: embedding gather + 128-step tanh recurrence. One block, 512 threads =
// 32 batch chains x 16 hidden units. idx in LDS; embeddings prefetched 4 deep.
// Per-step deps stay inside a 16-lane group -> same-wave LDS ordering, no
// per-step barrier (validated rounds 1/3/4/5).
// ---------------------------------------------------------------------------
__global__ __launch_bounds__(512) void rnn_recur(
    const int* __restrict__ idx, const float* __restrict__ lookup,
    const float* __restrict__ Wx, const float* __restrict__ Wh,
    float* __restrict__ Hout)
{
    __shared__ float sWx[EMB][HID];
    __shared__ float sWh[HID][HID];
    __shared__ float sH[BATCH][HID];
    __shared__ float sX[BATCH][EMB + 1];
    __shared__ int   sIdx[SEQ * BATCH];  // 16 KB

    const int tid = threadIdx.x;
    const int b = tid >> 4, j = tid & 15;

    sWx[tid >> 4][tid & 15] = Wx[tid];
    if (tid < HID * HID) sWh[tid >> 4][tid & 15] = Wh[tid];
    sH[b][j] = 1.0f;  // torch inits H to ones
    #pragma unroll
    for (int i = tid; i < SEQ * BATCH; i += 512) sIdx[i] = idx[i];
    __syncthreads();

    const int el = 2 * j;  // thread (b,j) owns X[t][b][2j..2j+1]
    float2 x0 = *(const float2*)(lookup + sIdx[0 * BATCH + b] * EMB + el);
    float2 x1 = *(const float2*)(lookup + sIdx[1 * BATCH + b] * EMB + el);
    float2 x2 = *(const float2*)(lookup + sIdx[2 * BATCH + b] * EMB + el);
    float2 x3 = *(const float2*)(lookup + sIdx[3 * BATCH + b] * EMB + el);

#define RNN_STEP(XR, T)                                                     \
    {                                                                       \
        sX[b][el] = XR.x; sX[b][el + 1] = XR.y;                             \
        if ((T) + 4 < SEQ) {                                                \
            int row = sIdx[((T) + 4) * BATCH + b];                          \
            XR = *(const float2*)(lookup + row * EMB + el);                 \
        }                                                                   \
        float a0 = 0.f, a1 = 0.f, a2 = 0.f, a3 = 0.f;                       \
        _Pragma("unroll")                                                   \
        for (int e = 0; e < EMB; e += 4) {                                  \
            a0 += sX[b][e + 0] * sWx[e + 0][j];                             \
            a1 += sX[b][e + 1] * sWx[e + 1][j];                             \
            a2 += sX[b][e + 2] * sWx[e + 2][j];                             \
            a3 += sX[b][e + 3] * sWx[e + 3][j];                             \
        }                                                                   \
        _Pragma("unroll")                                                   \
        for (int k = 0; k < HID; k += 4) {                                  \
            a0 += sH[b][k + 0] * sWh[k + 0][j];                             \
            a1 += sH[b][k + 1] * sWh[k + 1][j];                             \
            a2 += sH[b][k + 2] * sWh[k + 2][j];                             \
            a3 += sH[b][k + 3] * sWh[k + 3][j];                             \
        }                                                                   \
        float a = (a0 + a1) + (a2 + a3);                                    \
        float e2 = __expf(2.f * a);      /* tanh = 1 - 2/(e^{2a}+1) */      \
        float h = 1.f - 2.f / (e2 + 1.f);                                   \
        sH[b][j] = h;                                                       \
        Hout[(T) * (BATCH * HID) + tid] = h;                                \
    }

    for (int t = 0; t < SEQ; t += 4) {
        RNN_STEP(x0, t + 0)
        RNN_STEP(x1, t + 1)
        RNN_STEP(x2, t + 2)
        RNN_STEP(x3, t + 3)
    }
#undef RNN_STEP
}

// ---------------------------------------------------------------------------
// K2: partial exp-sums, Wo slice in REGISTERS (L2 reuse of Wo is unwinnable
// against the output write stream — rounds 1-4; registers are cache-immune).
// Block = 2000-col slice (16 float4 = 64 VGPR, one HBM load) x 128 rows.
// Per row: 4-col exp-sum, wave shfl reduce, per-wave LDS slot, one barrier,
// cross-wave sum -> P[vtile][row]. Deterministic (each P written once).
// No max subtraction: H tanh-bounded => |logit| small, exp safe in f32.
// ---------------------------------------------------------------------------
#define RV 128   // rows per block
#define VSK 2000 // vocab cols per block slice (500 active threads x 4)

__global__ __launch_bounds__(512, 4) void sum_exp_partial(
    const float* __restrict__ H, const float* __restrict__ Wo,
    float* __restrict__ P)
{
    __shared__ __align__(16) float sH[RV * HID];  // 8 KB
    __shared__ float part[8][RV];                 // 4 KB, per-wave partials

    const int tid = threadIdx.x;
    const int wave = tid >> 6;
    const int vtile = blockIdx.x & 15;         // 16 x 2000 = 32000
    const int row0 = (blockIdx.x >> 4) * RV;   // 32 row chunks

    *(float4*)(sH + 4 * tid) = *(const float4*)(H + row0 * HID + 4 * tid);
    __syncthreads();

    const bool active = (4 * tid < VSK);
    const int v = vtile * VSK + (active ? 4 * tid : 0);  // clamp: no OOB
    float4 wo[HID];
    #pragma unroll
    for (int k = 0; k < HID; ++k)
        wo[k] = *(const float4*)(Wo + (size_t)k * VOCAB + v);
    const float amask = active ? 1.f : 0.f;

    for (int r = 0; r < RV; ++r) {
        float l0 = 0, l1 = 0, l2 = 0, l3 = 0;
        #pragma unroll
        for (int k = 0; k < HID; ++k) {
            float h = sH[r * HID + k];  // uniform addr: LDS broadcast
            l0 += h * wo[k].x; l1 += h * wo[k].y;
            l2 += h * wo[k].z; l3 += h * wo[k].w;
        }
        float s = amask * ((__expf(l0) + __expf(l1)) +
                           (__expf(l2) + __expf(l3)));
        #pragma unroll
        for (int off = 32; off > 0; off >>= 1)
            s += __shfl_xor(s, off);
        if ((tid & 63) == 0) part[wave][r] = s;  // own slot: no barrier
    }
    __syncthreads();
    if (tid < RV) {
        float tot = 0.f;
        #pragma unroll
        for (int w = 0; w < 8; ++w) tot += part[w][tid];
        P[(size_t)vtile * NROW + row0 + tid] = tot;
    }
}

// ---------------------------------------------------------------------------
// K3: output pass, Wo slice in registers; logS reduction FUSED (threads
// 0..127 sum the 16 P partials for this block's rows — coalesced 512 B
// reads — before the barrier). Output uses PLAIN float4 stores: NT stores
// showed 1.8x write amplification (WRITE 950-970 MB vs 524 ideal, rounds
// 3/4) and their L2-protection role is obsolete now that Wo is in regs.
// ---------------------------------------------------------------------------
__global__ __launch_bounds__(512, 4) void write_logits(
    const float* __restrict__ H, const float* __restrict__ Wo,
    const float* __restrict__ P, float* __restrict__ out)
{
    __shared__ __align__(16) float sH[RV * HID];  // 8 KB
    __shared__ float sLogS[RV];

    const int tid = threadIdx.x;
    const int vtile = blockIdx.x & 15;
    const int row0 = (blockIdx.x >> 4) * RV;
    const int vbase = vtile * VSK;

    *(float4*)(sH + 4 * tid) = *(const float4*)(H + row0 * HID + 4 * tid);
    if (tid < RV) {  // fused logS: sum 16 partials for row (row0+tid)
        float tot = 0.f;
        #pragma unroll
        for (int v = 0; v < 16; ++v) tot += P[(size_t)v * NROW + row0 + tid];
        sLogS[tid] = __logf(tot);
    }
    __syncthreads();

    if (tid >= VSK / 4) return;  // threads 500..511 done (no later barriers)

    const int v = vbase + 4 * tid;
    float4 wo[HID];
    #pragma unroll
    for (int k = 0; k < HID; ++k)
        wo[k] = *(const float4*)(Wo + (size_t)k * VOCAB + v);

    float* orow = out + (size_t)row0 * VOCAB + v;
    for (int r = 0; r < RV; ++r) {
        float l0 = 0, l1 = 0, l2 = 0, l3 = 0;
        #pragma unroll
        for (int k = 0; k < HID; ++k) {
            float h = sH[r * HID + k];  // uniform addr: LDS broadcast
            l0 += h * wo[k].x; l1 += h * wo[k].y;
            l2 += h * wo[k].z; l3 += h * wo[k].w;
        }
        float ls = sLogS[r];
        float4 o;
        o.x = l0 - ls; o.y = l1 - ls; o.z = l2 - ls; o.w = l3 - ls;
        *(float4*)orow = o;  // plain write-back store
        orow += VOCAB;
    }
}

extern "C" void kernel_launch(void* const* d_in, const int* in_sizes, int n_in,
                              void* d_out, int out_size, void* d_ws, size_t ws_size,
                              hipStream_t stream) {
    const int*   idx    = (const int*)d_in[0];    // [SEQ, BATCH] int32
    const float* lookup = (const float*)d_in[1];  // [VOCAB, EMB]
    const float* Wx     = (const float*)d_in[2];  // [EMB, HID]
    const float* Wh     = (const float*)d_in[3];  // [HID, HID]
    const float* Wo     = (const float*)d_in[4];  // [HID, VOCAB]
    float* out = (float*)d_out;                   // [SEQ, BATCH, VOCAB]

    // ws layout: H (256 KB) | P partials 16x4096 (256 KB)
    float* Hbuf = (float*)d_ws;
    float* P    = Hbuf + NROW * HID;

    rnn_recur<<<1, 512, 0, stream>>>(idx, lookup, Wx, Wh, Hbuf);
    sum_exp_partial<<<16 * (NROW / RV), 512, 0, stream>>>(Hbuf, Wo, P);
    write_logits<<<16 * (NROW / RV), 512, 0, stream>>>(Hbuf, Wo, P, out);
}

// Round 7
// 273.000 us; speedup vs baseline: 2.4181x; 2.4181x over previous
//
#include <hip/hip_runtime.h>

#define VOCAB 32000
#define EMB 32
#define HID 16
#define SEQ 128
#define BATCH 32
#define NROW (SEQ * BATCH)  // 4096 rows = (t, b) pairs

typedef float f32x4 __attribute__((ext_vector_type(4)));  // nontemporal-ok vec

// ---------------------------------------------------------------------------
// K1: embedding gather + 128-step tanh recurrence. One block, 512 threads =
// 32 batch chains x 16 hidden units. idx in LDS; embeddings prefetched 4 deep.
// Per-step deps stay inside a 16-lane group -> same-wave LDS ordering, no
// per-step barrier (validated rounds 1/3/4/5/6).
// ---------------------------------------------------------------------------
__global__ __launch_bounds__(512) void rnn_recur(
    const int* __restrict__ idx, const float* __restrict__ lookup,
    const float* __restrict__ Wx, const float* __restrict__ Wh,
    float* __restrict__ Hout)
{
    __shared__ float sWx[EMB][HID];
    __shared__ float sWh[HID][HID];
    __shared__ float sH[BATCH][HID];
    __shared__ float sX[BATCH][EMB + 1];
    __shared__ int   sIdx[SEQ * BATCH];  // 16 KB

    const int tid = threadIdx.x;
    const int b = tid >> 4, j = tid & 15;

    sWx[tid >> 4][tid & 15] = Wx[tid];
    if (tid < HID * HID) sWh[tid >> 4][tid & 15] = Wh[tid];
    sH[b][j] = 1.0f;  // torch inits H to ones
    #pragma unroll
    for (int i = tid; i < SEQ * BATCH; i += 512) sIdx[i] = idx[i];
    __syncthreads();

    const int el = 2 * j;  // thread (b,j) owns X[t][b][2j..2j+1]
    float2 x0 = *(const float2*)(lookup + sIdx[0 * BATCH + b] * EMB + el);
    float2 x1 = *(const float2*)(lookup + sIdx[1 * BATCH + b] * EMB + el);
    float2 x2 = *(const float2*)(lookup + sIdx[2 * BATCH + b] * EMB + el);
    float2 x3 = *(const float2*)(lookup + sIdx[3 * BATCH + b] * EMB + el);

#define RNN_STEP(XR, T)                                                     \
    {                                                                       \
        sX[b][el] = XR.x; sX[b][el + 1] = XR.y;                             \
        if ((T) + 4 < SEQ) {                                                \
            int row = sIdx[((T) + 4) * BATCH + b];                          \
            XR = *(const float2*)(lookup + row * EMB + el);                 \
        }                                                                   \
        float a0 = 0.f, a1 = 0.f, a2 = 0.f, a3 = 0.f;                       \
        _Pragma("unroll")                                                   \
        for (int e = 0; e < EMB; e += 4) {                                  \
            a0 += sX[b][e + 0] * sWx[e + 0][j];                             \
            a1 += sX[b][e + 1] * sWx[e + 1][j];                             \
            a2 += sX[b][e + 2] * sWx[e + 2][j];                             \
            a3 += sX[b][e + 3] * sWx[e + 3][j];                             \
        }                                                                   \
        _Pragma("unroll")                                                   \
        for (int k = 0; k < HID; k += 4) {                                  \
            a0 += sH[b][k + 0] * sWh[k + 0][j];                             \
            a1 += sH[b][k + 1] * sWh[k + 1][j];                             \
            a2 += sH[b][k + 2] * sWh[k + 2][j];                             \
            a3 += sH[b][k + 3] * sWh[k + 3][j];                             \
        }                                                                   \
        float a = (a0 + a1) + (a2 + a3);                                    \
        float e2 = __expf(2.f * a);      /* tanh = 1 - 2/(e^{2a}+1) */      \
        float h = 1.f - 2.f / (e2 + 1.f);                                   \
        sH[b][j] = h;                                                       \
        Hout[(T) * (BATCH * HID) + tid] = h;                                \
    }

    for (int t = 0; t < SEQ; t += 4) {
        RNN_STEP(x0, t + 0)
        RNN_STEP(x1, t + 1)
        RNN_STEP(x2, t + 2)
        RNN_STEP(x3, t + 3)
    }
#undef RNN_STEP
}

// ---------------------------------------------------------------------------
// Vocab tiling (both vocab passes): VSK=2048 = 512 threads x 4 cols, so every
// thread is active and every wave's 1024 B store/load span is 128B-aligned
// (vbase = vtile*8192 B, row stride 128000 B — both 128B multiples).
// 16 tiles x 2048 = 32768: tile 15 has a 1280-col tail (threads with
// v >= VOCAB masked/early-exited).
// Wo slice lives in REGISTERS (16 x float4 = 64 VGPR, one HBM load/block):
// L2 residency of Wo is unwinnable against the 524 MB output stream
// (rounds 1-4), and plain write-back output stores RFO-thrash L2 (round 6:
// FETCH 1.41 GB) -> NT stores + register-Wo is the only stable combination.
// ---------------------------------------------------------------------------
#define RV 128    // rows per block
#define VSK 2048  // vocab cols per block slice

// K2: partial exp-sums -> P[vtile][row]. Deterministic (each elem written
// once). No max subtraction: H tanh-bounded => |logit| small, exp safe f32.
__global__ __launch_bounds__(512, 4) void sum_exp_partial(
    const float* __restrict__ H, const float* __restrict__ Wo,
    float* __restrict__ P)
{
    __shared__ __align__(16) float sH[RV * HID];  // 8 KB
    __shared__ float part[8][RV];                 // 4 KB, per-wave partials

    const int tid = threadIdx.x;
    const int wave = tid >> 6;
    const int vtile = blockIdx.x & 15;         // 16 x 2048 >= 32000
    const int row0 = (blockIdx.x >> 4) * RV;   // 32 row chunks

    *(float4*)(sH + 4 * tid) = *(const float4*)(H + row0 * HID + 4 * tid);
    __syncthreads();

    const int v = vtile * VSK + 4 * tid;
    const bool active = (v < VOCAB);
    const int vc = active ? v : (VOCAB - 4);   // clamp: no OOB load
    float4 wo[HID];
    #pragma unroll
    for (int k = 0; k < HID; ++k)
        wo[k] = *(const float4*)(Wo + (size_t)k * VOCAB + vc);
    const float amask = active ? 1.f : 0.f;

    for (int r = 0; r < RV; ++r) {
        float l0 = 0, l1 = 0, l2 = 0, l3 = 0;
        #pragma unroll
        for (int k = 0; k < HID; ++k) {
            float h = sH[r * HID + k];  // uniform addr: LDS broadcast
            l0 += h * wo[k].x; l1 += h * wo[k].y;
            l2 += h * wo[k].z; l3 += h * wo[k].w;
        }
        float s = amask * ((__expf(l0) + __expf(l1)) +
                           (__expf(l2) + __expf(l3)));
        #pragma unroll
        for (int off = 32; off > 0; off >>= 1)
            s += __shfl_xor(s, off);
        if ((tid & 63) == 0) part[wave][r] = s;  // own slot: no barrier
    }
    __syncthreads();
    if (tid < RV) {
        float tot = 0.f;
        #pragma unroll
        for (int w = 0; w < 8; ++w) tot += part[w][tid];
        P[(size_t)vtile * NROW + row0 + tid] = tot;
    }
}

// K3: output pass. logS fused (threads 0..127 sum the 16 P partials for this
// block's rows before the barrier). NT float4 stores, fully 128B-aligned.
__global__ __launch_bounds__(512, 4) void write_logits(
    const float* __restrict__ H, const float* __restrict__ Wo,
    const float* __restrict__ P, float* __restrict__ out)
{
    __shared__ __align__(16) float sH[RV * HID];  // 8 KB
    __shared__ float sLogS[RV];

    const int tid = threadIdx.x;
    const int vtile = blockIdx.x & 15;
    const int row0 = (blockIdx.x >> 4) * RV;

    *(float4*)(sH + 4 * tid) = *(const float4*)(H + row0 * HID + 4 * tid);
    if (tid < RV) {  // fused logS: sum 16 partials for row (row0+tid)
        float tot = 0.f;
        #pragma unroll
        for (int p = 0; p < 16; ++p) tot += P[(size_t)p * NROW + row0 + tid];
        sLogS[tid] = __logf(tot);
    }
    __syncthreads();

    const int v = vtile * VSK + 4 * tid;
    if (v >= VOCAB) return;  // tile-15 tail; no barriers after this point

    float4 wo[HID];
    #pragma unroll
    for (int k = 0; k < HID; ++k)
        wo[k] = *(const float4*)(Wo + (size_t)k * VOCAB + v);

    float* orow = out + (size_t)row0 * VOCAB + v;
    for (int r = 0; r < RV; ++r) {
        float l0 = 0, l1 = 0, l2 = 0, l3 = 0;
        #pragma unroll
        for (int k = 0; k < HID; ++k) {
            float h = sH[r * HID + k];  // uniform addr: LDS broadcast
            l0 += h * wo[k].x; l1 += h * wo[k].y;
            l2 += h * wo[k].z; l3 += h * wo[k].w;
        }
        float ls = sLogS[r];
        f32x4 o;
        o.x = l0 - ls; o.y = l1 - ls; o.z = l2 - ls; o.w = l3 - ls;
        __builtin_nontemporal_store(o, (f32x4*)orow);
        orow += VOCAB;
    }
}

extern "C" void kernel_launch(void* const* d_in, const int* in_sizes, int n_in,
                              void* d_out, int out_size, void* d_ws, size_t ws_size,
                              hipStream_t stream) {
    const int*   idx    = (const int*)d_in[0];    // [SEQ, BATCH] int32
    const float* lookup = (const float*)d_in[1];  // [VOCAB, EMB]
    const float* Wx     = (const float*)d_in[2];  // [EMB, HID]
    const float* Wh     = (const float*)d_in[3];  // [HID, HID]
    const float* Wo     = (const float*)d_in[4];  // [HID, VOCAB]
    float* out = (float*)d_out;                   // [SEQ, BATCH, VOCAB]

    // ws layout: H (256 KB) | P partials 16x4096 (256 KB)
    float* Hbuf = (float*)d_ws;
    float* P    = Hbuf + NROW * HID;

    rnn_recur<<<1, 512, 0, stream>>>(idx, lookup, Wx, Wh, Hbuf);
    sum_exp_partial<<<16 * (NROW / RV), 512, 0, stream>>>(Hbuf, Wo, P);
    write_logits<<<16 * (NROW / RV), 512, 0, stream>>>(Hbuf, Wo, P, out);
}

// Round 8
// 272.797 us; speedup vs baseline: 2.4199x; 1.0007x over previous
//
#include <hip/hip_runtime.h>

#define VOCAB 32000
#define EMB 32
#define HID 16
#define SEQ 128
#define BATCH 32
#define NROW (SEQ * BATCH)  // 4096 rows = (t, b) pairs

typedef float f32x2 __attribute__((ext_vector_type(2)));
typedef float f32x4 __attribute__((ext_vector_type(4)));

// ---------------------------------------------------------------------------
// K1: embedding gather + 128-step tanh recurrence. One block, 512 threads =
// 32 batch chains x 16 hidden units. idx in LDS; embeddings prefetched 4 deep.
// Per-step deps stay inside a 16-lane group -> same-wave LDS ordering, no
// per-step barrier (validated rounds 1-7).
// ---------------------------------------------------------------------------
__global__ __launch_bounds__(512) void rnn_recur(
    const int* __restrict__ idx, const float* __restrict__ lookup,
    const float* __restrict__ Wx, const float* __restrict__ Wh,
    float* __restrict__ Hout)
{
    __shared__ float sWx[EMB][HID];
    __shared__ float sWh[HID][HID];
    __shared__ float sH[BATCH][HID];
    __shared__ float sX[BATCH][EMB + 1];
    __shared__ int   sIdx[SEQ * BATCH];  // 16 KB

    const int tid = threadIdx.x;
    const int b = tid >> 4, j = tid & 15;

    sWx[tid >> 4][tid & 15] = Wx[tid];
    if (tid < HID * HID) sWh[tid >> 4][tid & 15] = Wh[tid];
    sH[b][j] = 1.0f;  // torch inits H to ones
    #pragma unroll
    for (int i = tid; i < SEQ * BATCH; i += 512) sIdx[i] = idx[i];
    __syncthreads();

    const int el = 2 * j;  // thread (b,j) owns X[t][b][2j..2j+1]
    float2 x0 = *(const float2*)(lookup + sIdx[0 * BATCH + b] * EMB + el);
    float2 x1 = *(const float2*)(lookup + sIdx[1 * BATCH + b] * EMB + el);
    float2 x2 = *(const float2*)(lookup + sIdx[2 * BATCH + b] * EMB + el);
    float2 x3 = *(const float2*)(lookup + sIdx[3 * BATCH + b] * EMB + el);

#define RNN_STEP(XR, T)                                                     \
    {                                                                       \
        sX[b][el] = XR.x; sX[b][el + 1] = XR.y;                             \
        if ((T) + 4 < SEQ) {                                                \
            int row = sIdx[((T) + 4) * BATCH + b];                          \
            XR = *(const float2*)(lookup + row * EMB + el);                 \
        }                                                                   \
        float a0 = 0.f, a1 = 0.f, a2 = 0.f, a3 = 0.f;                       \
        _Pragma("unroll")                                                   \
        for (int e = 0; e < EMB; e += 4) {                                  \
            a0 += sX[b][e + 0] * sWx[e + 0][j];                             \
            a1 += sX[b][e + 1] * sWx[e + 1][j];                             \
            a2 += sX[b][e + 2] * sWx[e + 2][j];                             \
            a3 += sX[b][e + 3] * sWx[e + 3][j];                             \
        }                                                                   \
        _Pragma("unroll")                                                   \
        for (int k = 0; k < HID; k += 4) {                                  \
            a0 += sH[b][k + 0] * sWh[k + 0][j];                             \
            a1 += sH[b][k + 1] * sWh[k + 1][j];                             \
            a2 += sH[b][k + 2] * sWh[k + 2][j];                             \
            a3 += sH[b][k + 3] * sWh[k + 3][j];                             \
        }                                                                   \
        float a = (a0 + a1) + (a2 + a3);                                    \
        float e2 = __expf(2.f * a);      /* tanh = 1 - 2/(e^{2a}+1) */      \
        float h = 1.f - 2.f / (e2 + 1.f);                                   \
        sH[b][j] = h;                                                       \
        Hout[(T) * (BATCH * HID) + tid] = h;                                \
    }

    for (int t = 0; t < SEQ; t += 4) {
        RNN_STEP(x0, t + 0)
        RNN_STEP(x1, t + 1)
        RNN_STEP(x2, t + 2)
        RNN_STEP(x3, t + 3)
    }
#undef RNN_STEP
}

// ---------------------------------------------------------------------------
// Vocab passes. VSK=2048 = 512 threads x 4 cols (128B-aligned everywhere;
// tile 15 has a 1280-col tail). Wo slice in REGISTERS as f32x2 lo/hi pairs
// (64 VGPR, one HBM load/block): L2 is unwinnable vs the 524 MB output
// stream (rounds 1-6). Round-7 lesson: the hot loop was DS-pipe-bound
// (16 ds_read_b32/row/wave @ ~5.8cyc each) -> read H as 4x ds_read_b128 and
// use float2 packed math (v_pk_fma_f32) to halve VALU issue.
// ---------------------------------------------------------------------------
#define RV 128    // rows per block
#define VSK 2048  // vocab cols per block slice

// K2: partial exp-sums -> P[vtile][row]. Deterministic (each elem written
// once). No max subtraction: |logit| <= ~1.5 (H tanh-bounded), exp safe f32.
__global__ __launch_bounds__(512, 4) void sum_exp_partial(
    const float* __restrict__ H, const float* __restrict__ Wo,
    float* __restrict__ P)
{
    __shared__ __align__(16) float sH[RV * HID];  // 8 KB
    __shared__ float part[8][RV];                 // 4 KB, per-wave partials

    const int tid = threadIdx.x;
    const int wave = tid >> 6;
    const int vtile = blockIdx.x & 15;         // 16 x 2048 >= 32000
    const int row0 = (blockIdx.x >> 4) * RV;   // 32 row chunks

    *(float4*)(sH + 4 * tid) = *(const float4*)(H + row0 * HID + 4 * tid);
    __syncthreads();

    const int v = vtile * VSK + 4 * tid;
    const bool active = (v < VOCAB);
    const int vc = active ? v : (VOCAB - 4);   // clamp: no OOB load
    f32x2 wlo[HID], whi[HID];
    #pragma unroll
    for (int k = 0; k < HID; ++k) {
        f32x4 w4 = *(const f32x4*)(Wo + (size_t)k * VOCAB + vc);
        wlo[k] = w4.xy; whi[k] = w4.zw;
    }
    const float amask = active ? 1.f : 0.f;
    const f32x4* sH4 = (const f32x4*)sH;

    for (int r = 0; r < RV; ++r) {
        f32x2 l01 = {0.f, 0.f}, l23 = {0.f, 0.f};
        #pragma unroll
        for (int q = 0; q < 4; ++q) {
            f32x4 hv = sH4[r * 4 + q];  // uniform addr: one b128 broadcast
            l01 += hv.x * wlo[4*q+0]; l23 += hv.x * whi[4*q+0];
            l01 += hv.y * wlo[4*q+1]; l23 += hv.y * whi[4*q+1];
            l01 += hv.z * wlo[4*q+2]; l23 += hv.z * whi[4*q+2];
            l01 += hv.w * wlo[4*q+3]; l23 += hv.w * whi[4*q+3];
        }
        float s = amask * ((__expf(l01.x) + __expf(l01.y)) +
                           (__expf(l23.x) + __expf(l23.y)));
        #pragma unroll
        for (int off = 32; off > 0; off >>= 1)
            s += __shfl_xor(s, off);
        if ((tid & 63) == 0) part[wave][r] = s;  // own slot: no barrier
    }
    __syncthreads();
    if (tid < RV) {
        float tot = 0.f;
        #pragma unroll
        for (int w = 0; w < 8; ++w) tot += part[w][tid];
        P[(size_t)vtile * NROW + row0 + tid] = tot;
    }
}

// K3: output pass. logS fused (threads 0..127 sum the 16 P partials before
// the barrier). NT float4 stores (write-back stores RFO-thrash L2: round 6).
__global__ __launch_bounds__(512, 4) void write_logits(
    const float* __restrict__ H, const float* __restrict__ Wo,
    const float* __restrict__ P, float* __restrict__ out)
{
    __shared__ __align__(16) float sH[RV * HID];  // 8 KB
    __shared__ __align__(16) float sLogS[RV];

    const int tid = threadIdx.x;
    const int vtile = blockIdx.x & 15;
    const int row0 = (blockIdx.x >> 4) * RV;

    *(float4*)(sH + 4 * tid) = *(const float4*)(H + row0 * HID + 4 * tid);
    if (tid < RV) {  // fused logS: sum 16 partials for row (row0+tid)
        float tot = 0.f;
        #pragma unroll
        for (int p = 0; p < 16; ++p) tot += P[(size_t)p * NROW + row0 + tid];
        sLogS[tid] = __logf(tot);
    }
    __syncthreads();

    const int v = vtile * VSK + 4 * tid;
    if (v >= VOCAB) return;  // tile-15 tail; no barriers after this point

    f32x2 wlo[HID], whi[HID];
    #pragma unroll
    for (int k = 0; k < HID; ++k) {
        f32x4 w4 = *(const f32x4*)(Wo + (size_t)k * VOCAB + v);
        wlo[k] = w4.xy; whi[k] = w4.zw;
    }
    const f32x4* sH4 = (const f32x4*)sH;
    const f32x4* sLS4 = (const f32x4*)sLogS;

    float* orow = out + (size_t)row0 * VOCAB + v;
    for (int r4 = 0; r4 < RV; r4 += 4) {
        f32x4 ls4 = sLS4[r4 >> 2];  // one b128 broadcast per 4 rows
        #pragma unroll
        for (int rr = 0; rr < 4; ++rr) {
            const int r = r4 + rr;
            f32x2 l01 = {0.f, 0.f}, l23 = {0.f, 0.f};
            #pragma unroll
            for (int q = 0; q < 4; ++q) {
                f32x4 hv = sH4[r * 4 + q];  // uniform addr b128 broadcast
                l01 += hv.x * wlo[4*q+0]; l23 += hv.x * whi[4*q+0];
                l01 += hv.y * wlo[4*q+1]; l23 += hv.y * whi[4*q+1];
                l01 += hv.z * wlo[4*q+2]; l23 += hv.z * whi[4*q+2];
                l01 += hv.w * wlo[4*q+3]; l23 += hv.w * whi[4*q+3];
            }
            const float ls = (rr == 0) ? ls4.x : (rr == 1) ? ls4.y
                           : (rr == 2) ? ls4.z : ls4.w;
            f32x4 o;
            o.xy = l01 - ls;  // v_pk_add
            o.zw = l23 - ls;
            __builtin_nontemporal_store(o, (f32x4*)orow);
            orow += VOCAB;
        }
    }
}

extern "C" void kernel_launch(void* const* d_in, const int* in_sizes, int n_in,
                              void* d_out, int out_size, void* d_ws, size_t ws_size,
                              hipStream_t stream) {
    const int*   idx    = (const int*)d_in[0];    // [SEQ, BATCH] int32
    const float* lookup = (const float*)d_in[1];  // [VOCAB, EMB]
    const float* Wx     = (const float*)d_in[2];  // [EMB, HID]
    const float* Wh     = (const float*)d_in[3];  // [HID, HID]
    const float* Wo     = (const float*)d_in[4];  // [HID, VOCAB]
    float* out = (float*)d_out;                   // [SEQ, BATCH, VOCAB]

    // ws layout: H (256 KB) | P partials 16x4096 (256 KB)
    float* Hbuf = (float*)d_ws;
    float* P    = Hbuf + NROW * HID;

    rnn_recur<<<1, 512, 0, stream>>>(idx, lookup, Wx, Wh, Hbuf);
    sum_exp_partial<<<16 * (NROW / RV), 512, 0, stream>>>(Hbuf, Wo, P);
    write_logits<<<16 * (NROW / RV), 512, 0, stream>>>(Hbuf, Wo, P, out);
}

// Round 9
// 272.687 us; speedup vs baseline: 2.4209x; 1.0004x over previous
//
#include <hip/hip_runtime.h>

#define VOCAB 32000
#define EMB 32
#define HID 16
#define SEQ 128
#define BATCH 32
#define NROW (SEQ * BATCH)  // 4096 rows = (t, b) pairs

typedef float f32x2 __attribute__((ext_vector_type(2)));
typedef float f32x4 __attribute__((ext_vector_type(4)));

// ---------------------------------------------------------------------------
// K1: embedding gather + 128-step tanh recurrence. One block, 512 threads =
// 32 batch chains x 16 hidden units. idx in LDS; embeddings prefetched 4 deep.
// Per-step deps stay inside a 16-lane group -> same-wave LDS ordering, no
// per-step barrier (validated rounds 1-8).
// ---------------------------------------------------------------------------
__global__ __launch_bounds__(512) void rnn_recur(
    const int* __restrict__ idx, const float* __restrict__ lookup,
    const float* __restrict__ Wx, const float* __restrict__ Wh,
    float* __restrict__ Hout)
{
    __shared__ float sWx[EMB][HID];
    __shared__ float sWh[HID][HID];
    __shared__ float sH[BATCH][HID];
    __shared__ float sX[BATCH][EMB + 1];
    __shared__ int   sIdx[SEQ * BATCH];  // 16 KB

    const int tid = threadIdx.x;
    const int b = tid >> 4, j = tid & 15;

    sWx[tid >> 4][tid & 15] = Wx[tid];
    if (tid < HID * HID) sWh[tid >> 4][tid & 15] = Wh[tid];
    sH[b][j] = 1.0f;  // torch inits H to ones
    #pragma unroll
    for (int i = tid; i < SEQ * BATCH; i += 512) sIdx[i] = idx[i];
    __syncthreads();

    const int el = 2 * j;  // thread (b,j) owns X[t][b][2j..2j+1]
    float2 x0 = *(const float2*)(lookup + sIdx[0 * BATCH + b] * EMB + el);
    float2 x1 = *(const float2*)(lookup + sIdx[1 * BATCH + b] * EMB + el);
    float2 x2 = *(const float2*)(lookup + sIdx[2 * BATCH + b] * EMB + el);
    float2 x3 = *(const float2*)(lookup + sIdx[3 * BATCH + b] * EMB + el);

#define RNN_STEP(XR, T)                                                     \
    {                                                                       \
        sX[b][el] = XR.x; sX[b][el + 1] = XR.y;                             \
        if ((T) + 4 < SEQ) {                                                \
            int row = sIdx[((T) + 4) * BATCH + b];                          \
            XR = *(const float2*)(lookup + row * EMB + el);                 \
        }                                                                   \
        float a0 = 0.f, a1 = 0.f, a2 = 0.f, a3 = 0.f;                       \
        _Pragma("unroll")                                                   \
        for (int e = 0; e < EMB; e += 4) {                                  \
            a0 += sX[b][e + 0] * sWx[e + 0][j];                             \
            a1 += sX[b][e + 1] * sWx[e + 1][j];                             \
            a2 += sX[b][e + 2] * sWx[e + 2][j];                             \
            a3 += sX[b][e + 3] * sWx[e + 3][j];                             \
        }                                                                   \
        _Pragma("unroll")                                                   \
        for (int k = 0; k < HID; k += 4) {                                  \
            a0 += sH[b][k + 0] * sWh[k + 0][j];                             \
            a1 += sH[b][k + 1] * sWh[k + 1][j];                             \
            a2 += sH[b][k + 2] * sWh[k + 2][j];                             \
            a3 += sH[b][k + 3] * sWh[k + 3][j];                             \
        }                                                                   \
        float a = (a0 + a1) + (a2 + a3);                                    \
        float e2 = __expf(2.f * a);      /* tanh = 1 - 2/(e^{2a}+1) */      \
        float h = 1.f - 2.f / (e2 + 1.f);                                   \
        sH[b][j] = h;                                                       \
        Hout[(T) * (BATCH * HID) + tid] = h;                                \
    }

    for (int t = 0; t < SEQ; t += 4) {
        RNN_STEP(x0, t + 0)
        RNN_STEP(x1, t + 1)
        RNN_STEP(x2, t + 2)
        RNN_STEP(x3, t + 3)
    }
#undef RNN_STEP
}

// ---------------------------------------------------------------------------
// Vocab passes. VSK=2048 = 512 threads x 4 cols (128B-aligned; tile 15 has a
// 1280-col tail). Wo slice in REGISTERS (64 VGPR, one HBM load/block): L2 is
// unwinnable vs the 524 MB output stream (rounds 1-6); NT stores mandatory
// (round 6: write-back RFO-thrashes L2, FETCH 1.41 GB).
// Round-8 lesson: issue-count reduction changed nothing; kernels are
// LATENCY-bound at 50% occupancy (round 6: VALUBusy 9.9%, Occupancy 46.9%).
// -> RV 128->64: grid 1024 blocks = 4 blocks/CU = 32 waves/CU (100%) to
// hide the shuffle/store dependency chains with TLP.
// ---------------------------------------------------------------------------
#define RV 64     // rows per block
#define VSK 2048  // vocab cols per block slice

// K2: partial exp-sums -> P[vtile][row]. Deterministic (each elem written
// once). No max subtraction: |logit| <= ~1.5 (H tanh-bounded), exp safe f32.
__global__ __launch_bounds__(512, 4) void sum_exp_partial(
    const float* __restrict__ H, const float* __restrict__ Wo,
    float* __restrict__ P)
{
    __shared__ __align__(16) float sH[RV * HID];  // 4 KB
    __shared__ float part[8][RV];                 // 2 KB, per-wave partials

    const int tid = threadIdx.x;
    const int wave = tid >> 6;
    const int vtile = blockIdx.x & 15;         // 16 x 2048 >= 32000
    const int row0 = (blockIdx.x >> 4) * RV;   // 64 row chunks

    if (tid < RV * HID / 4)
        *(float4*)(sH + 4 * tid) = *(const float4*)(H + row0 * HID + 4 * tid);
    __syncthreads();

    const int v = vtile * VSK + 4 * tid;
    const bool active = (v < VOCAB);
    const int vc = active ? v : (VOCAB - 4);   // clamp: no OOB load
    f32x2 wlo[HID], whi[HID];
    #pragma unroll
    for (int k = 0; k < HID; ++k) {
        f32x4 w4 = *(const f32x4*)(Wo + (size_t)k * VOCAB + vc);
        wlo[k] = w4.xy; whi[k] = w4.zw;
    }
    const float amask = active ? 1.f : 0.f;
    const f32x4* sH4 = (const f32x4*)sH;

    for (int r = 0; r < RV; ++r) {
        f32x2 l01 = {0.f, 0.f}, l23 = {0.f, 0.f};
        #pragma unroll
        for (int q = 0; q < 4; ++q) {
            f32x4 hv = sH4[r * 4 + q];  // uniform addr: one b128 broadcast
            l01 += hv.x * wlo[4*q+0]; l23 += hv.x * whi[4*q+0];
            l01 += hv.y * wlo[4*q+1]; l23 += hv.y * whi[4*q+1];
            l01 += hv.z * wlo[4*q+2]; l23 += hv.z * whi[4*q+2];
            l01 += hv.w * wlo[4*q+3]; l23 += hv.w * whi[4*q+3];
        }
        float s = amask * ((__expf(l01.x) + __expf(l01.y)) +
                           (__expf(l23.x) + __expf(l23.y)));
        #pragma unroll
        for (int off = 32; off > 0; off >>= 1)
            s += __shfl_xor(s, off);
        if ((tid & 63) == 0) part[wave][r] = s;  // own slot: no barrier
    }
    __syncthreads();
    if (tid < RV) {
        float tot = 0.f;
        #pragma unroll
        for (int w = 0; w < 8; ++w) tot += part[w][tid];
        P[(size_t)vtile * NROW + row0 + tid] = tot;
    }
}

// K3: output pass. logS fused (threads 0..RV-1 sum the 16 P partials before
// the barrier). NT float4 stores.
__global__ __launch_bounds__(512, 4) void write_logits(
    const float* __restrict__ H, const float* __restrict__ Wo,
    const float* __restrict__ P, float* __restrict__ out)
{
    __shared__ __align__(16) float sH[RV * HID];  // 4 KB
    __shared__ __align__(16) float sLogS[RV];

    const int tid = threadIdx.x;
    const int vtile = blockIdx.x & 15;
    const int row0 = (blockIdx.x >> 4) * RV;

    if (tid < RV * HID / 4)
        *(float4*)(sH + 4 * tid) = *(const float4*)(H + row0 * HID + 4 * tid);
    if (tid < RV) {  // fused logS: sum 16 partials for row (row0+tid)
        float tot = 0.f;
        #pragma unroll
        for (int p = 0; p < 16; ++p) tot += P[(size_t)p * NROW + row0 + tid];
        sLogS[tid] = __logf(tot);
    }
    __syncthreads();

    const int v = vtile * VSK + 4 * tid;
    if (v >= VOCAB) return;  // tile-15 tail; no barriers after this point

    f32x2 wlo[HID], whi[HID];
    #pragma unroll
    for (int k = 0; k < HID; ++k) {
        f32x4 w4 = *(const f32x4*)(Wo + (size_t)k * VOCAB + v);
        wlo[k] = w4.xy; whi[k] = w4.zw;
    }
    const f32x4* sH4 = (const f32x4*)sH;
    const f32x4* sLS4 = (const f32x4*)sLogS;

    float* orow = out + (size_t)row0 * VOCAB + v;
    for (int r4 = 0; r4 < RV; r4 += 4) {
        f32x4 ls4 = sLS4[r4 >> 2];  // one b128 broadcast per 4 rows
        #pragma unroll
        for (int rr = 0; rr < 4; ++rr) {
            const int r = r4 + rr;
            f32x2 l01 = {0.f, 0.f}, l23 = {0.f, 0.f};
            #pragma unroll
            for (int q = 0; q < 4; ++q) {
                f32x4 hv = sH4[r * 4 + q];  // uniform addr b128 broadcast
                l01 += hv.x * wlo[4*q+0]; l23 += hv.x * whi[4*q+0];
                l01 += hv.y * wlo[4*q+1]; l23 += hv.y * whi[4*q+1];
                l01 += hv.z * wlo[4*q+2]; l23 += hv.z * whi[4*q+2];
                l01 += hv.w * wlo[4*q+3]; l23 += hv.w * whi[4*q+3];
            }
            const float ls = (rr == 0) ? ls4.x : (rr == 1) ? ls4.y
                           : (rr == 2) ? ls4.z : ls4.w;
            f32x4 o;
            o.xy = l01 - ls;  // v_pk_add
            o.zw = l23 - ls;
            __builtin_nontemporal_store(o, (f32x4*)orow);
            orow += VOCAB;
        }
    }
}

extern "C" void kernel_launch(void* const* d_in, const int* in_sizes, int n_in,
                              void* d_out, int out_size, void* d_ws, size_t ws_size,
                              hipStream_t stream) {
    const int*   idx    = (const int*)d_in[0];    // [SEQ, BATCH] int32
    const float* lookup = (const float*)d_in[1];  // [VOCAB, EMB]
    const float* Wx     = (const float*)d_in[2];  // [EMB, HID]
    const float* Wh     = (const float*)d_in[3];  // [HID, HID]
    const float* Wo     = (const float*)d_in[4];  // [HID, VOCAB]
    float* out = (float*)d_out;                   // [SEQ, BATCH, VOCAB]

    // ws layout: H (256 KB) | P partials 16x4096 (256 KB)
    float* Hbuf = (float*)d_ws;
    float* P    = Hbuf + NROW * HID;

    rnn_recur<<<1, 512, 0, stream>>>(idx, lookup, Wx, Wh, Hbuf);
    sum_exp_partial<<<16 * (NROW / RV), 512, 0, stream>>>(Hbuf, Wo, P);
    write_logits<<<16 * (NROW / RV), 512, 0, stream>>>(Hbuf, Wo, P, out);
}